// Round 1
// baseline (185.959 us; speedup 1.0000x reference)
//
#include <hip/hip_runtime.h>
#include <hip/hip_bf16.h>
#include <math.h>

// ChamferLoss: pred [32,4096,3] f32, gt [32,4096,3] f32 -> scalar f32
// out = mean_{b,m} min_n dist(pred[b,n], gt[b,m]) + mean_{b,n} min_m dist(...)
//
// Inner-loop trick: for a fixed query q, min_m d2 = p2 + min_m (g2[m] - 2*dot).
// So the per-pair cost is 3 FMA + 1 min; p2 and sqrt applied once per query.

#define TPB 256
#define QPT 4            // query points per thread -> 1024 queries per block
#define CHUNK 2048       // target points staged in LDS per pass (32 KB)
#define NPTS 4096
#define BATCH 32

__global__ __launch_bounds__(TPB) void chamfer_kernel(
    const float* __restrict__ pred,
    const float* __restrict__ gt,
    float* __restrict__ out)
{
    // grid.x = 256: [0,128) dir=0 (queries=pred, targets=gt, i.e. chamfer2),
    //               [128,256) dir=1 (queries=gt, targets=pred, chamfer1).
    const int bx   = blockIdx.x;
    const int dir  = bx >> 7;
    const int idx  = bx & 127;
    const int b    = idx >> 2;          // batch index (32)
    const int qblk = idx & 3;           // query block within batch (4 x 1024)

    const float* __restrict__ qbase = (dir ? gt : pred) + (size_t)b * NPTS * 3;
    const float* __restrict__ tbase = (dir ? pred : gt) + (size_t)b * NPTS * 3;

    __shared__ float4 sT[CHUNK];        // (-2x, -2y, -2z, x^2+y^2+z^2)
    __shared__ float swave[TPB / 64];

    const int tid = threadIdx.x;

    // Load this thread's query points (stride-256 within the 1024-query block)
    float qx[QPT], qy[QPT], qz[QPT], mn[QPT];
#pragma unroll
    for (int i = 0; i < QPT; ++i) {
        const int n = qblk * (TPB * QPT) + i * TPB + tid;
        const float* p = qbase + n * 3;
        qx[i] = p[0]; qy[i] = p[1]; qz[i] = p[2];
        mn[i] = 1e30f;                  // min over (g2 - 2*dot); can be negative
    }

    for (int c0 = 0; c0 < NPTS; c0 += CHUNK) {
        __syncthreads();
        // Stage CHUNK targets: each thread preprocesses CHUNK/TPB = 8 points
#pragma unroll
        for (int j = tid; j < CHUNK; j += TPB) {
            const float* tp = tbase + (c0 + j) * 3;
            float x = tp[0], y = tp[1], z = tp[2];
            sT[j] = make_float4(-2.0f * x, -2.0f * y, -2.0f * z,
                                fmaf(x, x, fmaf(y, y, z * z)));
        }
        __syncthreads();

        // Inner loop: 1 broadcast ds_read_b128 + 16 VALU per target
#pragma unroll 8
        for (int j = 0; j < CHUNK; ++j) {
            const float4 g = sT[j];
#pragma unroll
            for (int i = 0; i < QPT; ++i) {
                float d = fmaf(qx[i], g.x,
                          fmaf(qy[i], g.y,
                          fmaf(qz[i], g.z, g.w)));
                mn[i] = fminf(mn[i], d);
            }
        }
    }

    // Epilogue: finish d2 = min + p2, clamp, sqrt, accumulate
    float s = 0.0f;
#pragma unroll
    for (int i = 0; i < QPT; ++i) {
        float p2 = fmaf(qx[i], qx[i], fmaf(qy[i], qy[i], qz[i] * qz[i]));
        float d2 = mn[i] + p2;
        d2 = fmaxf(d2, 1e-12f);
        s += sqrtf(d2);
    }

    // Wave (64-lane) reduction, then cross-wave via LDS
#pragma unroll
    for (int off = 32; off > 0; off >>= 1)
        s += __shfl_down(s, off, 64);
    const int wid = tid >> 6, lane = tid & 63;
    if (lane == 0) swave[wid] = s;
    __syncthreads();
    if (tid == 0) {
        float tot = swave[0] + swave[1] + swave[2] + swave[3];
        // Both means are over 32*4096 = 131072 elements
        atomicAdd(out, tot * (1.0f / 131072.0f));
    }
}

extern "C" void kernel_launch(void* const* d_in, const int* in_sizes, int n_in,
                              void* d_out, int out_size, void* d_ws, size_t ws_size,
                              hipStream_t stream)
{
    const float* pred = (const float*)d_in[0];
    const float* gt   = (const float*)d_in[1];
    float* out        = (float*)d_out;

    // d_out is poisoned to 0xAA before every launch — zero it on-stream.
    hipMemsetAsync(d_out, 0, sizeof(float), stream);

    chamfer_kernel<<<dim3(256), dim3(TPB), 0, stream>>>(pred, gt, out);
}